// Round 13
// baseline (885.464 us; speedup 1.0000x reference)
//
#include <hip/hip_runtime.h>
#include <cstdint>

#define C_DIM 128
#define N_TOT 32768
#define TN 64
#define CHUNKS 8
#define TILE_N 512   // TN*CHUNKS
#define NTILES 64    // N_TOT / TILE_N

// workspace float offsets
#define WACC_OFF   0            // [2][2][128][128] unnormalized context
#define CSUM_OFF   65536        // [2][2][128] softmax-N denominators
#define WNORM_OFF  66048        // [2][2][128][128] normalized context
#define WS_ZERO_FLOATS 66048

// ---------------------------------------------------------------------------
// Kernel A: fused k/v projection + exp + partial E^T V accumulation.
// grid (64 tiles, B=2, S=2), 512 threads. Each block owns 512 n, 8 chunks of 64.
// ---------------------------------------------------------------------------
__global__ __launch_bounds__(512)
void ctx_kernel(const float* __restrict__ x0, const float* __restrict__ x1,
                const float* __restrict__ Wk0, const float* __restrict__ Wk1,
                const float* __restrict__ Wv0, const float* __restrict__ Wv1,
                float* __restrict__ ws)
{
    __shared__ float xs[C_DIM][68];   // x tile, [c][n] (pad 68: 16B-aligned rows)
    __shared__ float Es[TN][132];     // exp(Sk), n-major (pad 132)
    __shared__ float Vs[TN][132];     // V, n-major

    const int tile = blockIdx.x, b = blockIdx.y, s = blockIdx.z;
    const float* __restrict__ x  = s ? x1 : x0;
    const float* __restrict__ Wk = s ? Wk1 : Wk0;
    const float* __restrict__ Wv = s ? Wv1 : Wv0;

    const int tid  = threadIdx.x;
    const int lane = tid & 63;
    const int wave = __builtin_amdgcn_readfirstlane(tid >> 6);
    const int c0   = wave * 16;            // this wave's 16 output rows (projections)

    // stage-3 ownership: 8 c-groups of 16 rows x 64 d-pairs
    const int cg = (tid >> 6) * 16;
    const int d2 = (tid & 63) * 2;

    float acc3[16][2];
#pragma unroll
    for (int i = 0; i < 16; ++i) { acc3[i][0] = 0.f; acc3[i][1] = 0.f; }
    float csum = 0.f;

    const float* xb = x + (size_t)b * C_DIM * N_TOT + tile * TILE_N;

    for (int ch = 0; ch < CHUNKS; ++ch) {
        __syncthreads();                       // protect Es/Vs/xs from prev readers
        const int nb = ch * TN;
        // 128 rows x 16 float4/row = 2048 float4; 512 thr -> 4 each
#pragma unroll
        for (int it = 0; it < 4; ++it) {
            int idx = tid + it * 512;
            int r   = idx >> 4;                // [0,128)
            int c4  = (idx & 15) << 2;
            *(float4*)&xs[r][c4] = *(const float4*)(xb + (size_t)r * N_TOT + nb + c4);
        }
        __syncthreads();

        // ---- K projection + exp -> Es[n][c_out] ----
        {
            float a[16];
#pragma unroll
            for (int j = 0; j < 16; ++j) a[j] = 0.f;
            for (int c = 0; c < C_DIM; ++c) {
                float xv = xs[c][lane];
#pragma unroll
                for (int j = 0; j < 16; ++j)
                    a[j] = fmaf(Wk[(c0 + j) * C_DIM + c], xv, a[j]);   // uniform -> s_load
            }
#pragma unroll
            for (int j = 0; j < 16; ++j) a[j] = __expf(a[j]);          // scores ~N(0,0.23^2)
#pragma unroll
            for (int j = 0; j < 16; j += 4)
                *(float4*)&Es[lane][c0 + j] = make_float4(a[j], a[j+1], a[j+2], a[j+3]);
        }
        // ---- V projection -> Vs[n][d] ----
        {
            float a[16];
#pragma unroll
            for (int j = 0; j < 16; ++j) a[j] = 0.f;
            for (int c = 0; c < C_DIM; ++c) {
                float xv = xs[c][lane];
#pragma unroll
                for (int j = 0; j < 16; ++j)
                    a[j] = fmaf(Wv[(c0 + j) * C_DIM + c], xv, a[j]);
            }
#pragma unroll
            for (int j = 0; j < 16; j += 4)
                *(float4*)&Vs[lane][c0 + j] = make_float4(a[j], a[j+1], a[j+2], a[j+3]);
        }
        __syncthreads();

        // ---- colsum partial (softmax-N denominator) ----
        if (tid < C_DIM) {
            float sl = 0.f;
            for (int n = 0; n < TN; ++n) sl += Es[n][tid];
            csum += sl;
        }

        // ---- stage 3: acc3[c,d] += sum_n E[n][c] * V[n][d] ----
        for (int n = 0; n < TN; ++n) {
            float4 e0 = *(const float4*)&Es[n][cg + 0];
            float4 e1 = *(const float4*)&Es[n][cg + 4];
            float4 e2 = *(const float4*)&Es[n][cg + 8];
            float4 e3 = *(const float4*)&Es[n][cg + 12];
            float2 vv = *(const float2*)&Vs[n][d2];
            float ev[16] = {e0.x,e0.y,e0.z,e0.w, e1.x,e1.y,e1.z,e1.w,
                            e2.x,e2.y,e2.z,e2.w, e3.x,e3.y,e3.z,e3.w};
#pragma unroll
            for (int i = 0; i < 16; ++i) {
                acc3[i][0] = fmaf(ev[i], vv.x, acc3[i][0]);
                acc3[i][1] = fmaf(ev[i], vv.y, acc3[i][1]);
            }
        }
    }

    float* wacc = ws + WACC_OFF + (size_t)(s * 2 + b) * C_DIM * C_DIM;
    float* cs   = ws + CSUM_OFF + (s * 2 + b) * C_DIM;
    if (tid < C_DIM) atomicAdd(&cs[tid], csum);
#pragma unroll
    for (int i = 0; i < 16; ++i) {
        atomicAdd(&wacc[(cg + i) * C_DIM + d2 + 0], acc3[i][0]);
        atomicAdd(&wacc[(cg + i) * C_DIM + d2 + 1], acc3[i][1]);
    }
}

// ---------------------------------------------------------------------------
// Kernel B: w[c,d] = wacc[c,d] / colsum[c]
// ---------------------------------------------------------------------------
__global__ void norm_kernel(float* __restrict__ ws)
{
    int idx = blockIdx.x * 256 + threadIdx.x;   // 0..65535
    int sb  = idx >> 14;
    int cd  = idx & 16383;
    int c   = cd >> 7;
    float z = ws[CSUM_OFF + sb * C_DIM + c];
    ws[WNORM_OFF + idx] = ws[WACC_OFF + idx] / z;
}

// ---------------------------------------------------------------------------
// Kernel C: fused q projection + softmax-over-C + a = qsm @ w_other + fp32 store.
// ---------------------------------------------------------------------------
__global__ __launch_bounds__(512)
void out_kernel(const float* __restrict__ x0, const float* __restrict__ x1,
                const float* __restrict__ Wq0, const float* __restrict__ Wq1,
                const float* __restrict__ ws, float* __restrict__ out)
{
    __shared__ float xs[C_DIM][68];
    __shared__ float Qs[TN][132];     // scores then exp(q), n-major
    __shared__ float wo[C_DIM][132];  // other stream's normalized context
    __shared__ float zrow[TN];

    const int tile = blockIdx.x, b = blockIdx.y, s = blockIdx.z;
    const float* __restrict__ x  = s ? x1 : x0;
    const float* __restrict__ Wq = s ? Wq1 : Wq0;
    const float* __restrict__ wn = ws + WNORM_OFF + (size_t)((1 - s) * 2 + b) * C_DIM * C_DIM;
    float* __restrict__ outp = out + (size_t)s * 2 * C_DIM * N_TOT + (size_t)b * C_DIM * N_TOT;

    const int tid  = threadIdx.x;
    const int lane = tid & 63;
    const int wave = __builtin_amdgcn_readfirstlane(tid >> 6);
    const int c0   = wave * 16;

    // load w_other into LDS once (4096 float4)
#pragma unroll
    for (int it = 0; it < 8; ++it) {
        int idx = tid + it * 512;
        int r   = idx >> 5;
        int c4  = (idx & 31) << 2;
        *(float4*)&wo[r][c4] = *(const float4*)(wn + r * C_DIM + c4);
    }

    const float* xb = x + (size_t)b * C_DIM * N_TOT + tile * TILE_N;

    const int n4 = (tid & 15) << 2;   // 4 n per thread
    const int d4 = (tid >> 4) << 2;   // 4 d per thread

    for (int ch = 0; ch < CHUNKS; ++ch) {
        __syncthreads();
        const int nb = ch * TN;
        // 128 rows x 16 float4/row = 2048 float4; 512 thr -> 4 each
#pragma unroll
        for (int it = 0; it < 4; ++it) {
            int idx = tid + it * 512;
            int r   = idx >> 4;
            int c4  = (idx & 15) << 2;
            *(float4*)&xs[r][c4] = *(const float4*)(xb + (size_t)r * N_TOT + nb + c4);
        }
        __syncthreads();

        // ---- q projection -> Qs[n][c_out] ----
        {
            float a[16];
#pragma unroll
            for (int j = 0; j < 16; ++j) a[j] = 0.f;
            for (int c = 0; c < C_DIM; ++c) {
                float xv = xs[c][lane];
#pragma unroll
                for (int j = 0; j < 16; ++j)
                    a[j] = fmaf(Wq[(c0 + j) * C_DIM + c], xv, a[j]);
            }
#pragma unroll
            for (int j = 0; j < 16; j += 4)
                *(float4*)&Qs[lane][c0 + j] = make_float4(a[j], a[j+1], a[j+2], a[j+3]);
        }
        __syncthreads();

        // ---- softmax over c (128) per n: 8 threads per n ----
        {
            const int n  = tid >> 3;
            const int q8 = tid & 7;
            float v[16];
#pragma unroll
            for (int i = 0; i < 16; ++i) v[i] = Qs[n][q8 * 16 + i];
            float m = v[0];
#pragma unroll
            for (int i = 1; i < 16; ++i) m = fmaxf(m, v[i]);
            m = fmaxf(m, __shfl_xor(m, 1));
            m = fmaxf(m, __shfl_xor(m, 2));
            m = fmaxf(m, __shfl_xor(m, 4));
            float zs = 0.f;
#pragma unroll
            for (int i = 0; i < 16; ++i) { v[i] = __expf(v[i] - m); zs += v[i]; }
            zs += __shfl_xor(zs, 1);
            zs += __shfl_xor(zs, 2);
            zs += __shfl_xor(zs, 4);
#pragma unroll
            for (int i = 0; i < 16; i += 4)
                *(float4*)&Qs[n][q8 * 16 + i] = make_float4(v[i], v[i+1], v[i+2], v[i+3]);
            if (q8 == 0) zrow[n] = 1.f / zs;
        }
        __syncthreads();

        // ---- a[n,d] = (1/Z_n) * sum_c Qs[n][c] * wo[c][d]; out[b,d,n] = fp32 ----
        {
            float a4[4][4];
#pragma unroll
            for (int i = 0; i < 4; ++i)
#pragma unroll
                for (int j = 0; j < 4; ++j) a4[i][j] = 0.f;

            for (int c = 0; c < C_DIM; ++c) {
                float4 wv = *(const float4*)&wo[c][d4];
                float q0 = Qs[n4 + 0][c];
                float q1 = Qs[n4 + 1][c];
                float q2 = Qs[n4 + 2][c];
                float q3 = Qs[n4 + 3][c];
                a4[0][0] = fmaf(q0, wv.x, a4[0][0]); a4[0][1] = fmaf(q0, wv.y, a4[0][1]);
                a4[0][2] = fmaf(q0, wv.z, a4[0][2]); a4[0][3] = fmaf(q0, wv.w, a4[0][3]);
                a4[1][0] = fmaf(q1, wv.x, a4[1][0]); a4[1][1] = fmaf(q1, wv.y, a4[1][1]);
                a4[1][2] = fmaf(q1, wv.z, a4[1][2]); a4[1][3] = fmaf(q1, wv.w, a4[1][3]);
                a4[2][0] = fmaf(q2, wv.x, a4[2][0]); a4[2][1] = fmaf(q2, wv.y, a4[2][1]);
                a4[2][2] = fmaf(q2, wv.z, a4[2][2]); a4[2][3] = fmaf(q2, wv.w, a4[2][3]);
                a4[3][0] = fmaf(q3, wv.x, a4[3][0]); a4[3][1] = fmaf(q3, wv.y, a4[3][1]);
                a4[3][2] = fmaf(q3, wv.z, a4[3][2]); a4[3][3] = fmaf(q3, wv.w, a4[3][3]);
            }
            float z0 = zrow[n4 + 0], z1 = zrow[n4 + 1], z2 = zrow[n4 + 2], z3 = zrow[n4 + 3];
#pragma unroll
            for (int j = 0; j < 4; ++j) {
                float4 o;
                o.x = a4[0][j] * z0; o.y = a4[1][j] * z1;
                o.z = a4[2][j] * z2; o.w = a4[3][j] * z3;
                *(float4*)(outp + (size_t)(d4 + j) * N_TOT + tile * TILE_N + nb + n4) = o;
            }
        }
    }
}

// ---------------------------------------------------------------------------
extern "C" void kernel_launch(void* const* d_in, const int* in_sizes, int n_in,
                              void* d_out, int out_size, void* d_ws, size_t ws_size,
                              hipStream_t stream)
{
    (void)in_sizes; (void)n_in; (void)out_size; (void)ws_size;
    const float* x0  = (const float*)d_in[0];
    const float* x1  = (const float*)d_in[1];
    const float* Wk0 = (const float*)d_in[2];
    const float* Wk1 = (const float*)d_in[3];
    const float* Wq0 = (const float*)d_in[4];
    const float* Wq1 = (const float*)d_in[5];
    const float* Wv0 = (const float*)d_in[6];
    const float* Wv1 = (const float*)d_in[7];
    float* wsf  = (float*)d_ws;
    float* outf = (float*)d_out;

    hipMemsetAsync(d_ws, 0, WS_ZERO_FLOATS * sizeof(float), stream);
    ctx_kernel <<<dim3(NTILES, 2, 2), 512, 0, stream>>>(x0, x1, Wk0, Wk1, Wv0, Wv1, wsf);
    norm_kernel<<<dim3(256), dim3(256), 0, stream>>>(wsf);
    out_kernel <<<dim3(NTILES, 2, 2), 512, 0, stream>>>(x0, x1, Wq0, Wq1, wsf, outf);
}